// Round 16
// baseline (784.906 us; speedup 1.0000x reference)
//
#include <hip/hip_runtime.h>
#include <math.h>

#define E 192
#define DI 384
#define S 16
#define R 12
#define DEPTH 4
#define P 400
#define NC 20
#define BATCH 32
#define L 401
#define NTOK (BATCH * L)   // 12832
#define CH 32
#define NCH 13             // ceil(401/32)

using short8 = __attribute__((ext_vector_type(8))) short;
using float4v = __attribute__((ext_vector_type(4))) float;

__device__ __forceinline__ float siluf(float x) {
    return x / (1.f + __expf(-x));
}
__device__ __forceinline__ float softplusf(float x) {
    return (x > 20.f) ? x : log1pf(__expf(x));
}
// f32 -> bf16 round-to-nearest-even (bit-level; no __hip_bfloat16 dep)
__device__ __forceinline__ unsigned short f2bf(float x) {
    unsigned int u = __float_as_uint(x);
    unsigned int r = 0x7fffu + ((u >> 16) & 1u);
    return (unsigned short)((u + r) >> 16);
}
__device__ __forceinline__ float bf2f(unsigned short v) {
    return __uint_as_float(((unsigned int)v) << 16);
}

// ---------------------------------------------------------------------------
// K0: patch embed + pos + depthwise conv3 + cls token  -> resid[b,l,e]
// ---------------------------------------------------------------------------
__global__ void k_embed(const float* __restrict__ imgs, const float* __restrict__ patch_w,
                        const float* __restrict__ patch_b, const float* __restrict__ cls_token,
                        const float* __restrict__ pos_embed, const float* __restrict__ cnn_w,
                        const float* __restrict__ cnn_b, float* __restrict__ resid) {
    int idx = blockIdx.x * blockDim.x + threadIdx.x;
    if (idx >= NTOK * E) return;
    int e = idx % E;
    int bl = idx / E;
    int l = bl % L;
    int b = bl / L;
    float out;
    if (l == P) {
        out = cls_token[e] + pos_embed[(size_t)P * E + e];
    } else {
        float w0 = patch_w[e * 4 + 0], w1 = patch_w[e * 4 + 1];
        float w2 = patch_w[e * 4 + 2], w3 = patch_w[e * 4 + 3];
        float pb = patch_b[e];
        const float* ib = imgs + (size_t)b * 1600;
        auto xe = [&](int ll) -> float {
            const float* ip = ib + ll * 4;
            return ip[0] * w0 + ip[1] * w1 + ip[2] * w2 + ip[3] * w3 + pb +
                   pos_embed[(size_t)ll * E + e];
        };
        float c0 = cnn_w[e * 3 + 0], c1 = cnn_w[e * 3 + 1], c2 = cnn_w[e * 3 + 2];
        float acc = cnn_b[e] + xe(l) * c1;
        if (l > 0) acc += xe(l - 1) * c0;
        if (l < P - 1) acc += xe(l + 1) * c2;
        out = acc;
    }
    resid[idx] = out;
}

// ---------------------------------------------------------------------------
// K_prep: weight bf16 conversions (in_proj with norm_w FOLDED in: rmsnorm is
// per-row scaling x per-K weight; the per-K weight is linear in the GEMM) +
// transposed negA ([layer][n][d]) + transposed dt weights ([layer][r][d]).
// ---------------------------------------------------------------------------
__global__ void k_prep(const float* __restrict__ in_proj_w, const float* __restrict__ x_proj_w,
                       const float* __restrict__ out_proj_w, const float* __restrict__ A_log,
                       const float* __restrict__ dt_proj_w, const float* __restrict__ norm_w,
                       unsigned short* __restrict__ w_in, unsigned short* __restrict__ w_x,
                       unsigned short* __restrict__ w_out, float* __restrict__ negA,
                       float* __restrict__ dtw_t) {
    const int n1 = DEPTH * 2 * DI * E;
    const int n2 = DEPTH * 44 * DI;
    const int n3 = DEPTH * E * DI;
    const int n4 = DEPTH * DI * S;
    const int n5 = DEPTH * DI * R;
    int idx = blockIdx.x * blockDim.x + threadIdx.x;
    if (idx < n1) {
        int layer = idx / (2 * DI * E);
        int e = idx % E;
        w_in[idx] = f2bf(in_proj_w[idx] * norm_w[layer * E + e]);
    } else if (idx < n1 + n2) {
        int i = idx - n1;
        w_x[i] = f2bf(x_proj_w[i]);
    } else if (idx < n1 + n2 + n3) {
        int i = idx - n1 - n2;
        w_out[i] = f2bf(out_proj_w[i]);
    } else if (idx < n1 + n2 + n3 + n4) {
        int i = idx - n1 - n2 - n3;
        int layer = i / (DI * S);
        int rem = i % (DI * S);
        int n = rem / DI;
        int d = rem % DI;
        negA[i] = -__expf(A_log[(size_t)layer * DI * S + d * S + n]);
    } else if (idx < n1 + n2 + n3 + n4 + n5) {
        int i = idx - n1 - n2 - n3 - n4;
        int layer = i / (DI * R);
        int rem = i % (DI * R);
        int r = rem / DI;
        int d = rem % DI;
        dtw_t[i] = dt_proj_w[(size_t)layer * DI * R + d * R + r];
    }
}

// K_flag: per (layer,d): is a_n == (n+1)*a_0 for all n? -> pow-chain eligible
__global__ void k_flag(const float* __restrict__ negA, int* __restrict__ flag) {
    int idx = blockIdx.x * blockDim.x + threadIdx.x;
    if (idx >= DEPTH * DI) return;
    int layer = idx / DI;
    int d = idx % DI;
    const float* base = negA + (size_t)layer * DI * S;
    float a0 = base[d];
    bool ok = true;
#pragma unroll
    for (int n = 1; n < S; n++) {
        float an = base[n * DI + d];
        ok = ok && (fabsf(an - (float)(n + 1) * a0) <= 1e-5f * fabsf(an));
    }
    flag[idx] = ok ? 1 : 0;
}

// ---------------------------------------------------------------------------
// K2: bf16 MFMA GEMM  C = A[M,K](bf16) * W[N,K](bf16)^T
// block 256 (4 waves, 2x2 over (M,N)), tile BM x BN, BK=64.
// EPI=0: C[M,N] f32.  EPI=2: C[M,N] += acc  (out_proj residual accumulate)
// ---------------------------------------------------------------------------
template <int BM, int BN, int EPI>
__global__ __launch_bounds__(256) void k_gemm_bf16(const unsigned short* __restrict__ A,
                                                   const unsigned short* __restrict__ W,
                                                   float* __restrict__ C,
                                                   int M, int N, int K) {
    constexpr int BK = 64, PADK = BK + 8;
    constexpr int MT = BM / 32, NT = BN / 32;
    __shared__ unsigned short As[BM][PADK];
    __shared__ unsigned short Bs[BN][PADK];
    int tid = threadIdx.x;
    int m0 = blockIdx.y * BM, n0 = blockIdx.x * BN;
    int wave = tid >> 6, lane = tid & 63;
    int row16 = lane & 15, quad = lane >> 4;
    int wm0 = (wave >> 1) * (BM / 2), wn0 = (wave & 1) * (BN / 2);

    float4v acc[MT][NT];
#pragma unroll
    for (int i = 0; i < MT; i++)
#pragma unroll
        for (int j = 0; j < NT; j++) acc[i][j] = (float4v){0.f, 0.f, 0.f, 0.f};

    for (int k0 = 0; k0 < K; k0 += BK) {
#pragma unroll
        for (int p = 0; p < MT; p++) {
            int idx = (p * 256 + tid) * 8;
            int row = idx / BK, col = idx % BK;
            int gm = m0 + row;
            short8 v;
            if (gm < M)
                v = *(const short8*)&A[(size_t)gm * K + k0 + col];
            else
                v = (short8)0;
            *(short8*)&As[row][col] = v;
        }
#pragma unroll
        for (int p = 0; p < NT; p++) {
            int idx = (p * 256 + tid) * 8;
            int row = idx / BK, col = idx % BK;
            int gn = n0 + row;
            short8 v;
            if (gn < N)
                v = *(const short8*)&W[(size_t)gn * K + k0 + col];
            else
                v = (short8)0;
            *(short8*)&Bs[row][col] = v;
        }
        __syncthreads();
#pragma unroll
        for (int kk = 0; kk < BK; kk += 32) {
            int koff = kk + quad * 8;
            short8 af[MT], bfr[NT];
#pragma unroll
            for (int i = 0; i < MT; i++)
                af[i] = *(const short8*)&As[wm0 + i * 16 + row16][koff];
#pragma unroll
            for (int j = 0; j < NT; j++)
                bfr[j] = *(const short8*)&Bs[wn0 + j * 16 + row16][koff];
#pragma unroll
            for (int i = 0; i < MT; i++)
#pragma unroll
                for (int j = 0; j < NT; j++)
                    acc[i][j] = __builtin_amdgcn_mfma_f32_16x16x32_bf16(af[i], bfr[j],
                                                                        acc[i][j], 0, 0, 0);
        }
        __syncthreads();
    }
#pragma unroll
    for (int i = 0; i < MT; i++) {
#pragma unroll
        for (int j = 0; j < NT; j++) {
#pragma unroll
            for (int r = 0; r < 4; r++) {
                int m = m0 + wm0 + i * 16 + quad * 4 + r;
                int n = n0 + wn0 + j * 16 + row16;
                if (m >= M || n >= N) continue;
                float v = acc[i][j][r];
                if (EPI == 0)
                    C[(size_t)m * N + n] = v;
                else
                    C[(size_t)m * N + n] += v;  // residual accumulate
            }
        }
    }
}

// ---------------------------------------------------------------------------
// K2in: in_proj GEMM with rmsnorm FUSED via linearity:
//   hn = resid * scale_row * norm_w  =>  in_proj(hn) = scale_row * (resid @ W'^T)
// where W' has norm_w folded in (k_prep). Stages resid f32->bf16, accumulates
// per-row sumsq during staging, reduces to scale_row in LDS, applies in
// epilogue. Split output: n<DI -> xm bf16, n>=DI -> z bf16.
// BM=128, BN=64, K=E=192 (3 BK iters). Grid (12, ceil(M/128)).
// ---------------------------------------------------------------------------
__global__ __launch_bounds__(256) void k_gemm_inproj(
        const float* __restrict__ resid, const unsigned short* __restrict__ W,
        unsigned short* __restrict__ XM, unsigned short* __restrict__ Z, int M) {
    constexpr int BM = 128, BN = 64, BK = 64, PADK = BK + 8;
    constexpr int MT = 4, NT = 2;
    const int N = 2 * DI, K = E;
    __shared__ unsigned short As[BM][PADK];
    __shared__ unsigned short Bs[BN][PADK];
    __shared__ float red[BM][8];
    __shared__ float rscale[BM];
    int tid = threadIdx.x;
    int m0 = blockIdx.y * BM, n0 = blockIdx.x * BN;
    int wave = tid >> 6, lane = tid & 63;
    int row16 = lane & 15, quad = lane >> 4;
    int wm0 = (wave >> 1) * (BM / 2), wn0 = (wave & 1) * (BN / 2);

    float4v acc[MT][NT];
#pragma unroll
    for (int i = 0; i < MT; i++)
#pragma unroll
        for (int j = 0; j < NT; j++) acc[i][j] = (float4v){0.f, 0.f, 0.f, 0.f};
    float ss[MT] = {0.f, 0.f, 0.f, 0.f};

    for (int k0 = 0; k0 < K; k0 += BK) {
        // stage A: f32 load + sumsq + bf16 convert. row = 32p + tid/8.
#pragma unroll
        for (int p = 0; p < MT; p++) {
            int idx = (p * 256 + tid) * 8;
            int row = idx / BK, col = idx % BK;
            int gm = m0 + row;
            float v[8];
            if (gm < M) {
                const float* src = &resid[(size_t)gm * K + k0 + col];
#pragma unroll
                for (int q = 0; q < 8; q++) v[q] = src[q];
            } else {
#pragma unroll
                for (int q = 0; q < 8; q++) v[q] = 0.f;
            }
            short8 sv;
#pragma unroll
            for (int q = 0; q < 8; q++) {
                ss[p] += v[q] * v[q];
                sv[q] = (short)f2bf(v[q]);
            }
            *(short8*)&As[row][col] = sv;
        }
        // stage B (grid exact in N, but keep the check)
#pragma unroll
        for (int p = 0; p < NT; p++) {
            int idx = (p * 256 + tid) * 8;
            int row = idx / BK, col = idx % BK;
            int gn = n0 + row;
            short8 v;
            if (gn < N)
                v = *(const short8*)&W[(size_t)gn * K + k0 + col];
            else
                v = (short8)0;
            *(short8*)&Bs[row][col] = v;
        }
        __syncthreads();
#pragma unroll
        for (int kk = 0; kk < BK; kk += 32) {
            int koff = kk + quad * 8;
            short8 af[MT], bfr[NT];
#pragma unroll
            for (int i = 0; i < MT; i++)
                af[i] = *(const short8*)&As[wm0 + i * 16 + row16][koff];
#pragma unroll
            for (int j = 0; j < NT; j++)
                bfr[j] = *(const short8*)&Bs[wn0 + j * 16 + row16][koff];
#pragma unroll
            for (int i = 0; i < MT; i++)
#pragma unroll
                for (int j = 0; j < NT; j++)
                    acc[i][j] = __builtin_amdgcn_mfma_f32_16x16x32_bf16(af[i], bfr[j],
                                                                        acc[i][j], 0, 0, 0);
        }
        __syncthreads();
    }
    // reduce per-row sumsq (8 partials per row) -> rscale
#pragma unroll
    for (int p = 0; p < MT; p++) red[32 * p + (tid >> 3)][tid & 7] = ss[p];
    __syncthreads();
    if (tid < BM) {
        float s = 0.f;
#pragma unroll
        for (int q = 0; q < 8; q++) s += red[tid][q];
        rscale[tid] = rsqrtf(s * (1.f / (float)E) + 1e-5f);
    }
    __syncthreads();
    // epilogue: scale rows, split xm/z
#pragma unroll
    for (int i = 0; i < MT; i++) {
#pragma unroll
        for (int j = 0; j < NT; j++) {
#pragma unroll
            for (int r = 0; r < 4; r++) {
                int lrow = wm0 + i * 16 + quad * 4 + r;
                int m = m0 + lrow;
                int n = n0 + wn0 + j * 16 + row16;
                if (m >= M) continue;
                float v = acc[i][j][r] * rscale[lrow];
                if (n < DI)
                    XM[(size_t)m * DI + n] = f2bf(v);
                else
                    Z[(size_t)m * DI + (n - DI)] = f2bf(v);
            }
        }
    }
}

// ---------------------------------------------------------------------------
// K3: causal depthwise conv4 + SiLU over xm(bf16) -> xc_bf (bf16)
// ---------------------------------------------------------------------------
__global__ void k_conv(const unsigned short* __restrict__ xm_bf, const float* __restrict__ cw,
                       const float* __restrict__ cb, unsigned short* __restrict__ xc_bf) {
    int idx = blockIdx.x * blockDim.x + threadIdx.x;
    if (idx >= NTOK * DI) return;
    int d = idx % DI;
    int bl = idx / DI;
    int l = bl % L;
    int b = bl / L;
    const unsigned short* base = xm_bf + (size_t)b * L * DI + d;
    float acc = cb[d];
#pragma unroll
    for (int k = 0; k < 4; k++) {
        int ll = l - 3 + k;
        if (ll >= 0) acc += bf2f(base[(size_t)ll * DI]) * cw[d * 4 + k];
    }
    xc_bf[idx] = f2bf(siluf(acc));
}

// ---------------------------------------------------------------------------
// K_dtpre: one block per token. dt = softplus(xdb_row . dtw_t + dtb) -> f32.
// (Throughput-parallel; transcendentals OFF the scan's serial path.)
// ---------------------------------------------------------------------------
__global__ __launch_bounds__(384) void k_dtpre(
        const float* __restrict__ xdb, const float* __restrict__ dtw_t,
        const float* __restrict__ dtb, float* __restrict__ dtbuf) {
    int tok = blockIdx.x;
    int d = threadIdx.x;
    const float* xr = xdb + (size_t)tok * 44;
    float acc = dtb[d];
#pragma unroll
    for (int r = 0; r < R; r++) acc += xr[r] * dtw_t[r * DI + d];
    dtbuf[(size_t)tok * DI + d] = softplusf(acc);
}

// ---------------------------------------------------------------------------
// K4a: chunk-local scan; fast path: e1=exp(a0*dt) computed cross-step,
// hidden under the h-chain. hend in [b][ch][n][d]. Writes packed ydt.
// LAST=true: only write ydt at t==P and chunk-last tokens.
// grid (NCH, BATCH) x 384 threads (d per thread).
// ---------------------------------------------------------------------------
template <bool LAST>
__global__ __launch_bounds__(384) void k_scanA(
        const unsigned short* __restrict__ xc_bf, const float* __restrict__ xdb,
        const float* __restrict__ dtbuf, const float* __restrict__ negA_l,
        const int* __restrict__ flag_l, const float* __restrict__ Dskip,
        float2* __restrict__ ydt, float* __restrict__ hend) {
    int d = threadIdx.x;
    int ch = blockIdx.x;
    int b = blockIdx.y;
    int t0 = ch * CH;
    int t1 = min(t0 + CH, L);
    bool fast = __all(flag_l[d] != 0);
    float a0 = negA_l[d];
    float a[S];
    if (!fast) {
#pragma unroll
        for (int n = 0; n < S; n++) a[n] = negA_l[n * DI + d];
    }
    float dsk = Dskip[d];
    float h[S] = {};
    float dts = 0.f;
    size_t tok0 = (size_t)b * L + t0;
    float dt_nx = dtbuf[tok0 * DI + d];
    float u_nx = bf2f(xc_bf[tok0 * DI + d]);
    float e1_nx = __expf(a0 * dt_nx);
    for (int t = t0; t < t1; t++) {
        size_t tok = (size_t)b * L + t;
        float dtv = dt_nx, e1v = e1_nx, uu = u_nx;
        if (t + 1 < t1) {  // prefetch + exp for next step, hidden by h-chain
            dt_nx = dtbuf[(tok + 1) * DI + d];
            u_nx = bf2f(xc_bf[(tok + 1) * DI + d]);
            e1_nx = __expf(a0 * dt_nx);
        }
        const float* row = xdb + tok * 44;   // block-uniform -> s_loads
        dts += dtv;
        float dtu = dtv * uu;
        float y = uu * dsk;
        if (fast) {
            float p = e1v;
#pragma unroll
            for (int n = 0; n < S; n++) {
                h[n] = p * h[n] + dtu * row[R + n];
                y += h[n] * row[R + S + n];
                p *= e1v;
            }
        } else {
#pragma unroll
            for (int n = 0; n < S; n++) {
                float dA = __expf(dtv * a[n]);
                h[n] = dA * h[n] + dtu * row[R + n];
                y += h[n] * row[R + S + n];
            }
        }
        if (!LAST || t == P || t == t1 - 1) ydt[tok * DI + d] = make_float2(y, dts);
    }
    float* he = hend + ((size_t)(b * NCH + ch) * S) * DI + d;
#pragma unroll
    for (int n = 0; n < S; n++) he[n * DI] = h[n];
}

// ---------------------------------------------------------------------------
// K4b: combine chunk prefixes serially (NCH chunks) -> h_init per chunk.
// ---------------------------------------------------------------------------
__global__ void k_scanB(const float* __restrict__ hend, const float2* __restrict__ ydt,
                        const float* __restrict__ negA_l, const int* __restrict__ flag_l,
                        float* __restrict__ hinit) {
    int idx = blockIdx.x * blockDim.x + threadIdx.x;
    if (idx >= BATCH * DI) return;
    int d = idx % DI;
    int b = idx / DI;
    bool fast = __all(flag_l[d] != 0);
    float a[S];
#pragma unroll
    for (int n = 0; n < S; n++) a[n] = negA_l[n * DI + d];
    float h[S] = {};
    for (int ch = 0; ch < NCH; ch++) {
        size_t o = ((size_t)(b * NCH + ch) * S) * DI + d;
#pragma unroll
        for (int n = 0; n < S; n++) hinit[o + n * DI] = h[n];
        int tlast = min(ch * CH + CH, L) - 1;
        float dts = ydt[((size_t)b * L + tlast) * DI + d].y;
        if (fast) {
            float e1c = __expf(a[0] * dts);
            float p = e1c;
#pragma unroll
            for (int n = 0; n < S; n++) {
                h[n] = p * h[n] + hend[o + n * DI];
                p *= e1c;
            }
        } else {
#pragma unroll
            for (int n = 0; n < S; n++) h[n] = __expf(dts * a[n]) * h[n] + hend[o + n * DI];
        }
    }
}

// ---------------------------------------------------------------------------
// K4c: fixup, one block per token: y = (y_local + sum_n c_n exp(a_n dtcum) h0_n)
//      * silu(z) -> bf16.
// ---------------------------------------------------------------------------
__global__ __launch_bounds__(384) void k_fixup(
        const unsigned short* __restrict__ z_bf, const float* __restrict__ xdb,
        const float* __restrict__ negA_l, const int* __restrict__ flag_l,
        const float* __restrict__ hinit, const float2* __restrict__ ydt,
        unsigned short* __restrict__ y_bf) {
    int tok = blockIdx.x;
    int d = threadIdx.x;
    int l = tok % L;
    int b = tok / L;
    int ch = l / CH;
    size_t idx = (size_t)tok * DI + d;
    float2 yd = ydt[idx];
    float y = yd.x;
    if (ch != 0) {
        bool fast = __all(flag_l[d] != 0);
        const float* h0 = hinit + ((size_t)(b * NCH + ch) * S) * DI + d;
        const float* cv = xdb + (size_t)tok * 44 + R + S;  // block-uniform
        float dts = yd.y;
        float corr = 0.f;
        if (fast) {
            float e1c = __expf(negA_l[d] * dts);
            float p = e1c;
#pragma unroll
            for (int n = 0; n < S; n++) {
                corr += cv[n] * p * h0[n * DI];
                p *= e1c;
            }
        } else {
#pragma unroll
            for (int n = 0; n < S; n++)
                corr += cv[n] * __expf(negA_l[n * DI + d] * dts) * h0[n * DI];
        }
        y += corr;
    }
    float z = bf2f(z_bf[idx]);
    y_bf[idx] = f2bf(y * siluf(z));
}

// ---------------------------------------------------------------------------
// K4c-last: fixup only for the 32 cls tokens (b*L+P) -> compact y32 [b][d]
// ---------------------------------------------------------------------------
__global__ __launch_bounds__(384) void k_fixup_last(
        const unsigned short* __restrict__ z_bf, const float* __restrict__ xdb,
        const float* __restrict__ negA_l, const int* __restrict__ flag_l,
        const float* __restrict__ hinit, const float2* __restrict__ ydt,
        unsigned short* __restrict__ y32) {
    int b = blockIdx.x;
    int d = threadIdx.x;
    int tok = b * L + P;
    int ch = P / CH;   // last chunk
    size_t idx = (size_t)tok * DI + d;
    float2 yd = ydt[idx];
    float y = yd.x;
    {
        bool fast = __all(flag_l[d] != 0);
        const float* h0 = hinit + ((size_t)(b * NCH + ch) * S) * DI + d;
        const float* cv = xdb + (size_t)tok * 44 + R + S;
        float dts = yd.y;
        float corr = 0.f;
        if (fast) {
            float e1c = __expf(negA_l[d] * dts);
            float p = e1c;
#pragma unroll
            for (int n = 0; n < S; n++) {
                corr += cv[n] * p * h0[n * DI];
                p *= e1c;
            }
        } else {
#pragma unroll
            for (int n = 0; n < S; n++)
                corr += cv[n] * __expf(negA_l[n * DI + d] * dts) * h0[n * DI];
        }
        y += corr;
    }
    float z = bf2f(z_bf[idx]);
    y32[(size_t)b * DI + d] = f2bf(y * siluf(z));
}

// ---------------------------------------------------------------------------
// K5: final rmsnorm of token 400 of (resid+hidden32), then head matmul -> out
// ---------------------------------------------------------------------------
__global__ void k_head(const float* __restrict__ resid, const float* __restrict__ hidden32,
                       const float* __restrict__ norm_f_w, const float* __restrict__ head_w,
                       const float* __restrict__ head_b, float* __restrict__ out) {
    __shared__ float v[E];
    int b = blockIdx.x;
    int lane = threadIdx.x;
    size_t base = ((size_t)b * L + P) * E;
    float loc[3];
    float ss = 0.f;
#pragma unroll
    for (int j = 0; j < 3; j++) {
        int e = lane + j * 64;
        float x = resid[base + e] + hidden32[(size_t)b * E + e];
        loc[j] = x;
        ss += x * x;
    }
#pragma unroll
    for (int off = 32; off > 0; off >>= 1) ss += __shfl_xor(ss, off, 64);
    float scale = rsqrtf(ss * (1.f / (float)E) + 1e-5f);
#pragma unroll
    for (int j = 0; j < 3; j++) {
        int e = lane + j * 64;
        v[e] = loc[j] * scale * norm_f_w[e];
    }
    __syncthreads();
    if (lane < NC) {
        float acc = head_b[lane];
        for (int e = 0; e < E; e++) acc += v[e] * head_w[lane * E + e];
        out[b * NC + lane] = acc;
    }
}

// ---------------------------------------------------------------------------
extern "C" void kernel_launch(void* const* d_in, const int* in_sizes, int n_in,
                              void* d_out, int out_size, void* d_ws, size_t ws_size,
                              hipStream_t stream) {
    const float* imgs      = (const float*)d_in[0];
    const float* patch_w   = (const float*)d_in[1];
    const float* patch_b   = (const float*)d_in[2];
    const float* cls_token = (const float*)d_in[3];
    const float* pos_embed = (const float*)d_in[4];
    const float* cnn_w     = (const float*)d_in[5];
    const float* cnn_b     = (const float*)d_in[6];
    const float* norm_w    = (const float*)d_in[7];
    const float* in_proj_w = (const float*)d_in[8];
    const float* conv_w    = (const float*)d_in[9];
    const float* conv_b    = (const float*)d_in[10];
    const float* x_proj_w  = (const float*)d_in[11];
    const float* dt_proj_w = (const float*)d_in[12];
    const float* dt_proj_b = (const float*)d_in[13];
    const float* A_log     = (const float*)d_in[14];
    const float* Dskip     = (const float*)d_in[15];
    const float* out_proj_w= (const float*)d_in[16];
    const float* norm_f_w  = (const float*)d_in[17];
    const float* head_w    = (const float*)d_in[18];
    const float* head_b    = (const float*)d_in[19];

    float* ws = (float*)d_ws;
    size_t off = 0;
    float* resid  = ws + off; off += (size_t)NTOK * E;
    float* xdb    = ws + off; off += (size_t)NTOK * 44;
    float* dtbuf  = ws + off; off += (size_t)NTOK * DI;             // f32 dt only
    float* ydt    = ws + off; off += (size_t)NTOK * DI * 2;  // packed {y_local,dtcum}
    float* hend   = ws + off; off += (size_t)BATCH * NCH * DI * S;  // [b][ch][n][d]
    float* hinit  = ws + off; off += (size_t)BATCH * NCH * DI * S;  // [b][ch][n][d]
    float* negA   = ws + off; off += (size_t)DEPTH * DI * S;        // [layer][n][d]
    float* dtw_t  = ws + off; off += (size_t)DEPTH * DI * R;        // [layer][r][d]
    float* hid32  = ws + off; off += (size_t)BATCH * E;             // compact last hidden
    int*   gflag  = (int*)(ws + off); off += (size_t)DEPTH * DI;    // [layer][d]
    unsigned short* xm_bf  = (unsigned short*)(ws + off); off += (size_t)NTOK * DI / 2;
    unsigned short* z_bf   = (unsigned short*)(ws + off); off += (size_t)NTOK * DI / 2;
    unsigned short* bf_buf = (unsigned short*)(ws + off); off += (size_t)NTOK * DI / 2;
    unsigned short* y32_bf = (unsigned short*)(ws + off); off += (size_t)BATCH * DI / 2 + 16;
    unsigned short* w_in  = (unsigned short*)(ws + off); off += (size_t)DEPTH * 2 * DI * E / 2;
    unsigned short* w_x   = (unsigned short*)(ws + off); off += (size_t)DEPTH * 44 * DI / 2 + 16;
    unsigned short* w_out = (unsigned short*)(ws + off); off += (size_t)DEPTH * E * DI / 2;

    // shared bf16 buffer, disjoint live ranges:
    // xc_bf: conv -> scanA; y_bf: fixup -> out_proj
    unsigned short* xc_bf = bf_buf;   // [NTOK, DI]
    unsigned short* y_bf  = bf_buf;   // [NTOK, DI]

    {
        int ntot = DEPTH * (2 * DI * E + 44 * DI + E * DI + DI * S + DI * R);
        k_prep<<<(ntot + 255) / 256, 256, 0, stream>>>(in_proj_w, x_proj_w, out_proj_w, A_log,
                                                       dt_proj_w, norm_w, w_in, w_x, w_out,
                                                       negA, dtw_t);
        k_flag<<<(DEPTH * DI + 255) / 256, 256, 0, stream>>>(negA, gflag);
    }

    k_embed<<<(NTOK * E) / 256, 256, 0, stream>>>(imgs, patch_w, patch_b, cls_token,
                                                  pos_embed, cnn_w, cnn_b, resid);

    for (int i = 0; i < DEPTH; i++) {
        // in_proj with FUSED rmsnorm (linearity: scale applied in epilogue,
        // norm_w folded into w_in at prep) -> xm bf16 + z bf16
        {
            dim3 g((2 * DI) / 64, (NTOK + 127) / 128);
            k_gemm_inproj<<<g, 256, 0, stream>>>(resid, w_in + (size_t)i * 2 * DI * E,
                                                 xm_bf, z_bf, NTOK);
        }
        // causal conv4 + silu -> xc_bf
        k_conv<<<(NTOK * DI) / 256, 256, 0, stream>>>(xm_bf, conv_w + (size_t)i * DI * 4,
                                                      conv_b + (size_t)i * DI, xc_bf);
        // x_proj: [NTOK,384]bf16 x [44,384]bf16^T -> xdb f32 [NTOK,44]
        {
            dim3 g(1, NTOK / 32);
            k_gemm_bf16<32, 64, 0><<<g, 256, 0, stream>>>(
                xc_bf, w_x + (size_t)i * 44 * DI, xdb, NTOK, 44, DI);
        }
        const float* nA = negA + (size_t)i * DI * S;
        const int* fl = gflag + (size_t)i * DI;
        // dt_proj + softplus -> f32 dt (block per token, throughput-parallel)
        k_dtpre<<<NTOK, 384, 0, stream>>>(xdb, dtw_t + (size_t)i * DI * R,
                                          dt_proj_b + (size_t)i * DI, dtbuf);
        // chunked scan: local scan -> chunk combine -> parallel fixup
        dim3 g(NCH, BATCH);
        if (i < DEPTH - 1) {
            k_scanA<false><<<g, DI, 0, stream>>>(xc_bf, xdb, dtbuf, nA, fl,
                                                 Dskip + (size_t)i * DI, (float2*)ydt, hend);
            k_scanB<<<(BATCH * DI + 255) / 256, 256, 0, stream>>>(hend, (const float2*)ydt,
                                                                  nA, fl, hinit);
            k_fixup<<<NTOK, 384, 0, stream>>>(z_bf, xdb, nA, fl, hinit,
                                              (const float2*)ydt, y_bf);
            // out_proj + residual accumulate: resid += y_bf @ w_out^T
            dim3 go(E / 64, (NTOK + 63) / 64);
            k_gemm_bf16<64, 64, 2><<<go, 256, 0, stream>>>(
                y_bf, w_out + (size_t)i * E * DI, resid, NTOK, E, DI);
        } else {
            // last layer: only the cls token (P) of each batch feeds the head
            k_scanA<true><<<g, DI, 0, stream>>>(xc_bf, xdb, dtbuf, nA, fl,
                                                Dskip + (size_t)i * DI, (float2*)ydt, hend);
            k_scanB<<<(BATCH * DI + 255) / 256, 256, 0, stream>>>(hend, (const float2*)ydt,
                                                                  nA, fl, hinit);
            k_fixup_last<<<BATCH, 384, 0, stream>>>(z_bf, xdb, nA, fl, hinit,
                                                    (const float2*)ydt, y32_bf);
            // out_proj on 32 rows only: [32,384] x [192,384]^T -> hid32 [32,192]
            dim3 go(E / 64, 1);
            k_gemm_bf16<32, 64, 0><<<go, 256, 0, stream>>>(
                y32_bf, w_out + (size_t)i * E * DI, hid32, BATCH, E, DI);
        }
    }

    k_head<<<BATCH, 64, 0, stream>>>(resid, hid32, norm_f_w, head_w, head_b, (float*)d_out);
}

// Round 17
// 729.161 us; speedup vs baseline: 1.0765x; 1.0765x over previous
//
#include <hip/hip_runtime.h>
#include <math.h>

#define E 192
#define DI 384
#define S 16
#define R 12
#define DEPTH 4
#define P 400
#define NC 20
#define BATCH 32
#define L 401
#define NTOK (BATCH * L)   // 12832
#define CH 32
#define NCH 13             // ceil(401/32)

using short8 = __attribute__((ext_vector_type(8))) short;
using float4v = __attribute__((ext_vector_type(4))) float;

__device__ __forceinline__ float siluf(float x) {
    return x / (1.f + __expf(-x));
}
__device__ __forceinline__ float softplusf(float x) {
    return (x > 20.f) ? x : log1pf(__expf(x));
}
// f32 -> bf16 round-to-nearest-even (bit-level; no __hip_bfloat16 dep)
__device__ __forceinline__ unsigned short f2bf(float x) {
    unsigned int u = __float_as_uint(x);
    unsigned int r = 0x7fffu + ((u >> 16) & 1u);
    return (unsigned short)((u + r) >> 16);
}
__device__ __forceinline__ float bf2f(unsigned short v) {
    return __uint_as_float(((unsigned int)v) << 16);
}

// ---------------------------------------------------------------------------
// K0: patch embed + pos + depthwise conv3 + cls token  -> resid[b,l,e]
// ---------------------------------------------------------------------------
__global__ void k_embed(const float* __restrict__ imgs, const float* __restrict__ patch_w,
                        const float* __restrict__ patch_b, const float* __restrict__ cls_token,
                        const float* __restrict__ pos_embed, const float* __restrict__ cnn_w,
                        const float* __restrict__ cnn_b, float* __restrict__ resid) {
    int idx = blockIdx.x * blockDim.x + threadIdx.x;
    if (idx >= NTOK * E) return;
    int e = idx % E;
    int bl = idx / E;
    int l = bl % L;
    int b = bl / L;
    float out;
    if (l == P) {
        out = cls_token[e] + pos_embed[(size_t)P * E + e];
    } else {
        float w0 = patch_w[e * 4 + 0], w1 = patch_w[e * 4 + 1];
        float w2 = patch_w[e * 4 + 2], w3 = patch_w[e * 4 + 3];
        float pb = patch_b[e];
        const float* ib = imgs + (size_t)b * 1600;
        auto xe = [&](int ll) -> float {
            const float* ip = ib + ll * 4;
            return ip[0] * w0 + ip[1] * w1 + ip[2] * w2 + ip[3] * w3 + pb +
                   pos_embed[(size_t)ll * E + e];
        };
        float c0 = cnn_w[e * 3 + 0], c1 = cnn_w[e * 3 + 1], c2 = cnn_w[e * 3 + 2];
        float acc = cnn_b[e] + xe(l) * c1;
        if (l > 0) acc += xe(l - 1) * c0;
        if (l < P - 1) acc += xe(l + 1) * c2;
        out = acc;
    }
    resid[idx] = out;
}

// ---------------------------------------------------------------------------
// K1: hn = rmsnorm(resid)*w -> bf16 (read-only resid; accumulate is in
// out_proj's EPI=2 epilogue). Separate kernel ON PURPOSE: fusing into
// in_proj (round 16) multiplies the sumsq/read cost by the N-tile count.
// ---------------------------------------------------------------------------
__global__ void k_rmsnorm(const float* __restrict__ resid, unsigned short* __restrict__ hn,
                          const float* __restrict__ w) {
    int wave = blockIdx.x * (blockDim.x >> 6) + (threadIdx.x >> 6);
    int lane = threadIdx.x & 63;
    if (wave >= NTOK) return;
    size_t base = (size_t)wave * E;
    float v[3];
    float ss = 0.f;
#pragma unroll
    for (int j = 0; j < 3; j++) {
        int e = lane + j * 64;
        float r = resid[base + e];
        v[j] = r;
        ss += r * r;
    }
#pragma unroll
    for (int off = 32; off > 0; off >>= 1) ss += __shfl_xor(ss, off, 64);
    float scale = rsqrtf(ss * (1.f / (float)E) + 1e-5f);
#pragma unroll
    for (int j = 0; j < 3; j++) {
        int e = lane + j * 64;
        hn[base + e] = f2bf(v[j] * scale * w[e]);
    }
}

// ---------------------------------------------------------------------------
// K_prep: weight bf16 conversions + transposed negA ([layer][n][d]) +
// transposed dt weights ([layer][r][d]) in one kernel.
// ---------------------------------------------------------------------------
__global__ void k_prep(const float* __restrict__ in_proj_w, const float* __restrict__ x_proj_w,
                       const float* __restrict__ out_proj_w, const float* __restrict__ A_log,
                       const float* __restrict__ dt_proj_w,
                       unsigned short* __restrict__ w_in, unsigned short* __restrict__ w_x,
                       unsigned short* __restrict__ w_out, float* __restrict__ negA,
                       float* __restrict__ dtw_t) {
    const int n1 = DEPTH * 2 * DI * E;
    const int n2 = DEPTH * 44 * DI;
    const int n3 = DEPTH * E * DI;
    const int n4 = DEPTH * DI * S;
    const int n5 = DEPTH * DI * R;
    int idx = blockIdx.x * blockDim.x + threadIdx.x;
    if (idx < n1) {
        w_in[idx] = f2bf(in_proj_w[idx]);
    } else if (idx < n1 + n2) {
        int i = idx - n1;
        w_x[i] = f2bf(x_proj_w[i]);
    } else if (idx < n1 + n2 + n3) {
        int i = idx - n1 - n2;
        w_out[i] = f2bf(out_proj_w[i]);
    } else if (idx < n1 + n2 + n3 + n4) {
        int i = idx - n1 - n2 - n3;
        int layer = i / (DI * S);
        int rem = i % (DI * S);
        int n = rem / DI;
        int d = rem % DI;
        negA[i] = -__expf(A_log[(size_t)layer * DI * S + d * S + n]);
    } else if (idx < n1 + n2 + n3 + n4 + n5) {
        int i = idx - n1 - n2 - n3 - n4;
        int layer = i / (DI * R);
        int rem = i % (DI * R);
        int r = rem / DI;
        int d = rem % DI;
        dtw_t[i] = dt_proj_w[(size_t)layer * DI * R + d * R + r];
    }
}

// K_flag: per (layer,d): is a_n == (n+1)*a_0 for all n? -> pow-chain eligible
__global__ void k_flag(const float* __restrict__ negA, int* __restrict__ flag) {
    int idx = blockIdx.x * blockDim.x + threadIdx.x;
    if (idx >= DEPTH * DI) return;
    int layer = idx / DI;
    int d = idx % DI;
    const float* base = negA + (size_t)layer * DI * S;
    float a0 = base[d];
    bool ok = true;
#pragma unroll
    for (int n = 1; n < S; n++) {
        float an = base[n * DI + d];
        ok = ok && (fabsf(an - (float)(n + 1) * a0) <= 1e-5f * fabsf(an));
    }
    flag[idx] = ok ? 1 : 0;
}

// ---------------------------------------------------------------------------
// K2: bf16 MFMA GEMM  C = A[M,K](bf16) * W[N,K](bf16)^T
// block 256 (4 waves, 2x2 over (M,N)), tile BM x BN, BK=64.
// EPI=0: C[M,N] f32.
// EPI=1 (in_proj split): n<DI -> XMbf16[m*DI+n] (xm), n>=DI -> Zbf16 (z gate).
// EPI=2: C[M,N] += acc  (out_proj fused residual accumulate)
// ---------------------------------------------------------------------------
template <int BM, int BN, int EPI>
__global__ __launch_bounds__(256) void k_gemm_bf16(const unsigned short* __restrict__ A,
                                                   const unsigned short* __restrict__ W,
                                                   float* __restrict__ C,
                                                   unsigned short* __restrict__ XM,
                                                   unsigned short* __restrict__ Z,
                                                   int M, int N, int K) {
    constexpr int BK = 64, PADK = BK + 8;
    constexpr int MT = BM / 32, NT = BN / 32;
    __shared__ unsigned short As[BM][PADK];
    __shared__ unsigned short Bs[BN][PADK];
    int tid = threadIdx.x;
    int m0 = blockIdx.y * BM, n0 = blockIdx.x * BN;
    int wave = tid >> 6, lane = tid & 63;
    int row16 = lane & 15, quad = lane >> 4;
    int wm0 = (wave >> 1) * (BM / 2), wn0 = (wave & 1) * (BN / 2);

    float4v acc[MT][NT];
#pragma unroll
    for (int i = 0; i < MT; i++)
#pragma unroll
        for (int j = 0; j < NT; j++) acc[i][j] = (float4v){0.f, 0.f, 0.f, 0.f};

    for (int k0 = 0; k0 < K; k0 += BK) {
#pragma unroll
        for (int p = 0; p < MT; p++) {
            int idx = (p * 256 + tid) * 8;
            int row = idx / BK, col = idx % BK;
            int gm = m0 + row;
            short8 v;
            if (gm < M)
                v = *(const short8*)&A[(size_t)gm * K + k0 + col];
            else
                v = (short8)0;
            *(short8*)&As[row][col] = v;
        }
#pragma unroll
        for (int p = 0; p < NT; p++) {
            int idx = (p * 256 + tid) * 8;
            int row = idx / BK, col = idx % BK;
            int gn = n0 + row;
            short8 v;
            if (gn < N)
                v = *(const short8*)&W[(size_t)gn * K + k0 + col];
            else
                v = (short8)0;
            *(short8*)&Bs[row][col] = v;
        }
        __syncthreads();
#pragma unroll
        for (int kk = 0; kk < BK; kk += 32) {
            int koff = kk + quad * 8;
            short8 af[MT], bfr[NT];
#pragma unroll
            for (int i = 0; i < MT; i++)
                af[i] = *(const short8*)&As[wm0 + i * 16 + row16][koff];
#pragma unroll
            for (int j = 0; j < NT; j++)
                bfr[j] = *(const short8*)&Bs[wn0 + j * 16 + row16][koff];
#pragma unroll
            for (int i = 0; i < MT; i++)
#pragma unroll
                for (int j = 0; j < NT; j++)
                    acc[i][j] = __builtin_amdgcn_mfma_f32_16x16x32_bf16(af[i], bfr[j],
                                                                        acc[i][j], 0, 0, 0);
        }
        __syncthreads();
    }
#pragma unroll
    for (int i = 0; i < MT; i++) {
#pragma unroll
        for (int j = 0; j < NT; j++) {
#pragma unroll
            for (int r = 0; r < 4; r++) {
                int m = m0 + wm0 + i * 16 + quad * 4 + r;
                int n = n0 + wn0 + j * 16 + row16;
                if (m >= M || n >= N) continue;
                float v = acc[i][j][r];
                if (EPI == 0) {
                    C[(size_t)m * N + n] = v;
                } else if (EPI == 1) {
                    if (n < DI)
                        XM[(size_t)m * DI + n] = f2bf(v);
                    else
                        Z[(size_t)m * DI + (n - DI)] = f2bf(v);
                } else {
                    C[(size_t)m * N + n] += v;  // residual accumulate
                }
            }
        }
    }
}

// ---------------------------------------------------------------------------
// K3: causal depthwise conv4 + SiLU over xm(bf16) -> xc_bf (bf16)
// ---------------------------------------------------------------------------
__global__ void k_conv(const unsigned short* __restrict__ xm_bf, const float* __restrict__ cw,
                       const float* __restrict__ cb, unsigned short* __restrict__ xc_bf) {
    int idx = blockIdx.x * blockDim.x + threadIdx.x;
    if (idx >= NTOK * DI) return;
    int d = idx % DI;
    int bl = idx / DI;
    int l = bl % L;
    int b = bl / L;
    const unsigned short* base = xm_bf + (size_t)b * L * DI + d;
    float acc = cb[d];
#pragma unroll
    for (int k = 0; k < 4; k++) {
        int ll = l - 3 + k;
        if (ll >= 0) acc += bf2f(base[(size_t)ll * DI]) * cw[d * 4 + k];
    }
    xc_bf[idx] = f2bf(siluf(acc));
}

// ---------------------------------------------------------------------------
// K_dtpre: one block per token. dt = softplus(xdb_row . dtw_t + dtb) -> f32.
// (Throughput-parallel; keeping transcendentals OFF the scan's serial path
//  -- round-14's fused version regressed 732->754.)
// ---------------------------------------------------------------------------
__global__ __launch_bounds__(384) void k_dtpre(
        const float* __restrict__ xdb, const float* __restrict__ dtw_t,
        const float* __restrict__ dtb, float* __restrict__ dtbuf) {
    int tok = blockIdx.x;
    int d = threadIdx.x;
    const float* xr = xdb + (size_t)tok * 44;
    float acc = dtb[d];
#pragma unroll
    for (int r = 0; r < R; r++) acc += xr[r] * dtw_t[r * DI + d];
    dtbuf[(size_t)tok * DI + d] = softplusf(acc);
}

// ---------------------------------------------------------------------------
// K4a: chunk-local scan; fast path: e1=exp(a0*dt) computed per step but
// issued right after the prefetched dt load -> hidden under h-chain.
// hend in [b][ch][n][d] layout. Writes packed ydt {y_local, dtcum}.
// LAST=true: only write ydt at t==P and chunk-last tokens.
// grid (NCH, BATCH) x 384 threads (d per thread).
// ---------------------------------------------------------------------------
template <bool LAST>
__global__ __launch_bounds__(384) void k_scanA(
        const unsigned short* __restrict__ xc_bf, const float* __restrict__ xdb,
        const float* __restrict__ dtbuf, const float* __restrict__ negA_l,
        const int* __restrict__ flag_l, const float* __restrict__ Dskip,
        float2* __restrict__ ydt, float* __restrict__ hend) {
    int d = threadIdx.x;
    int ch = blockIdx.x;
    int b = blockIdx.y;
    int t0 = ch * CH;
    int t1 = min(t0 + CH, L);
    bool fast = __all(flag_l[d] != 0);
    float a0 = negA_l[d];
    float a[S];
    if (!fast) {
#pragma unroll
        for (int n = 0; n < S; n++) a[n] = negA_l[n * DI + d];
    }
    float dsk = Dskip[d];
    float h[S] = {};
    float dts = 0.f;
    size_t tok0 = (size_t)b * L + t0;
    float dt_nx = dtbuf[tok0 * DI + d];
    float u_nx = bf2f(xc_bf[tok0 * DI + d]);
    float e1_nx = __expf(a0 * dt_nx);
    for (int t = t0; t < t1; t++) {
        size_t tok = (size_t)b * L + t;
        float dtv = dt_nx, e1v = e1_nx, uu = u_nx;
        if (t + 1 < t1) {  // prefetch + exp for next step, hidden by h-chain
            dt_nx = dtbuf[(tok + 1) * DI + d];
            u_nx = bf2f(xc_bf[(tok + 1) * DI + d]);
            e1_nx = __expf(a0 * dt_nx);
        }
        const float* row = xdb + tok * 44;   // block-uniform -> s_loads
        dts += dtv;
        float dtu = dtv * uu;
        float y = uu * dsk;
        if (fast) {
            float p = e1v;
#pragma unroll
            for (int n = 0; n < S; n++) {
                h[n] = p * h[n] + dtu * row[R + n];
                y += h[n] * row[R + S + n];
                p *= e1v;
            }
        } else {
#pragma unroll
            for (int n = 0; n < S; n++) {
                float dA = __expf(dtv * a[n]);
                h[n] = dA * h[n] + dtu * row[R + n];
                y += h[n] * row[R + S + n];
            }
        }
        if (!LAST || t == P || t == t1 - 1) ydt[tok * DI + d] = make_float2(y, dts);
    }
    float* he = hend + ((size_t)(b * NCH + ch) * S) * DI + d;
#pragma unroll
    for (int n = 0; n < S; n++) he[n * DI] = h[n];
}

// ---------------------------------------------------------------------------
// K4b: combine chunk prefixes serially (NCH chunks) -> h_init per chunk.
// ---------------------------------------------------------------------------
__global__ void k_scanB(const float* __restrict__ hend, const float2* __restrict__ ydt,
                        const float* __restrict__ negA_l, const int* __restrict__ flag_l,
                        float* __restrict__ hinit) {
    int idx = blockIdx.x * blockDim.x + threadIdx.x;
    if (idx >= BATCH * DI) return;
    int d = idx % DI;
    int b = idx / DI;
    bool fast = __all(flag_l[d] != 0);
    float a[S];
#pragma unroll
    for (int n = 0; n < S; n++) a[n] = negA_l[n * DI + d];
    float h[S] = {};
    for (int ch = 0; ch < NCH; ch++) {
        size_t o = ((size_t)(b * NCH + ch) * S) * DI + d;
#pragma unroll
        for (int n = 0; n < S; n++) hinit[o + n * DI] = h[n];
        int tlast = min(ch * CH + CH, L) - 1;
        float dts = ydt[((size_t)b * L + tlast) * DI + d].y;
        if (fast) {
            float e1c = __expf(a[0] * dts);
            float p = e1c;
#pragma unroll
            for (int n = 0; n < S; n++) {
                h[n] = p * h[n] + hend[o + n * DI];
                p *= e1c;
            }
        } else {
#pragma unroll
            for (int n = 0; n < S; n++) h[n] = __expf(dts * a[n]) * h[n] + hend[o + n * DI];
        }
    }
}

// ---------------------------------------------------------------------------
// K4c: fixup, one block per token: y = (y_local + sum_n c_n exp(a_n dtcum) h0_n)
//      * silu(z) -> bf16. cv row block-uniform; h0 coalesced; z from bf16.
// ---------------------------------------------------------------------------
__global__ __launch_bounds__(384) void k_fixup(
        const unsigned short* __restrict__ z_bf, const float* __restrict__ xdb,
        const float* __restrict__ negA_l, const int* __restrict__ flag_l,
        const float* __restrict__ hinit, const float2* __restrict__ ydt,
        unsigned short* __restrict__ y_bf) {
    int tok = blockIdx.x;
    int d = threadIdx.x;
    int l = tok % L;
    int b = tok / L;
    int ch = l / CH;
    size_t idx = (size_t)tok * DI + d;
    float2 yd = ydt[idx];
    float y = yd.x;
    if (ch != 0) {
        bool fast = __all(flag_l[d] != 0);
        const float* h0 = hinit + ((size_t)(b * NCH + ch) * S) * DI + d;
        const float* cv = xdb + (size_t)tok * 44 + R + S;  // block-uniform
        float dts = yd.y;
        float corr = 0.f;
        if (fast) {
            float e1c = __expf(negA_l[d] * dts);
            float p = e1c;
#pragma unroll
            for (int n = 0; n < S; n++) {
                corr += cv[n] * p * h0[n * DI];
                p *= e1c;
            }
        } else {
#pragma unroll
            for (int n = 0; n < S; n++)
                corr += cv[n] * __expf(negA_l[n * DI + d] * dts) * h0[n * DI];
        }
        y += corr;
    }
    float z = bf2f(z_bf[idx]);
    y_bf[idx] = f2bf(y * siluf(z));
}

// ---------------------------------------------------------------------------
// K4c-last: fixup only for the 32 cls tokens (b*L+P) -> compact y32 [b][d]
// ---------------------------------------------------------------------------
__global__ __launch_bounds__(384) void k_fixup_last(
        const unsigned short* __restrict__ z_bf, const float* __restrict__ xdb,
        const float* __restrict__ negA_l, const int* __restrict__ flag_l,
        const float* __restrict__ hinit, const float2* __restrict__ ydt,
        unsigned short* __restrict__ y32) {
    int b = blockIdx.x;
    int d = threadIdx.x;
    int tok = b * L + P;
    int ch = P / CH;   // last chunk
    size_t idx = (size_t)tok * DI + d;
    float2 yd = ydt[idx];
    float y = yd.x;
    {
        bool fast = __all(flag_l[d] != 0);
        const float* h0 = hinit + ((size_t)(b * NCH + ch) * S) * DI + d;
        const float* cv = xdb + (size_t)tok * 44 + R + S;
        float dts = yd.y;
        float corr = 0.f;
        if (fast) {
            float e1c = __expf(negA_l[d] * dts);
            float p = e1c;
#pragma unroll
            for (int n = 0; n < S; n++) {
                corr += cv[n] * p * h0[n * DI];
                p *= e1c;
            }
        } else {
#pragma unroll
            for (int n = 0; n < S; n++)
                corr += cv[n] * __expf(negA_l[n * DI + d] * dts) * h0[n * DI];
        }
        y += corr;
    }
    float z = bf2f(z_bf[idx]);
    y32[(size_t)b * DI + d] = f2bf(y * siluf(z));
}

// ---------------------------------------------------------------------------
// K5: final rmsnorm of token 400 of (resid+hidden32), then head matmul -> out
// ---------------------------------------------------------------------------
__global__ void k_head(const float* __restrict__ resid, const float* __restrict__ hidden32,
                       const float* __restrict__ norm_f_w, const float* __restrict__ head_w,
                       const float* __restrict__ head_b, float* __restrict__ out) {
    __shared__ float v[E];
    int b = blockIdx.x;
    int lane = threadIdx.x;
    size_t base = ((size_t)b * L + P) * E;
    float loc[3];
    float ss = 0.f;
#pragma unroll
    for (int j = 0; j < 3; j++) {
        int e = lane + j * 64;
        float x = resid[base + e] + hidden32[(size_t)b * E + e];
        loc[j] = x;
        ss += x * x;
    }
#pragma unroll
    for (int off = 32; off > 0; off >>= 1) ss += __shfl_xor(ss, off, 64);
    float scale = rsqrtf(ss * (1.f / (float)E) + 1e-5f);
#pragma unroll
    for (int j = 0; j < 3; j++) {
        int e = lane + j * 64;
        v[e] = loc[j] * scale * norm_f_w[e];
    }
    __syncthreads();
    if (lane < NC) {
        float acc = head_b[lane];
        for (int e = 0; e < E; e++) acc += v[e] * head_w[lane * E + e];
        out[b * NC + lane] = acc;
    }
}

// ---------------------------------------------------------------------------
extern "C" void kernel_launch(void* const* d_in, const int* in_sizes, int n_in,
                              void* d_out, int out_size, void* d_ws, size_t ws_size,
                              hipStream_t stream) {
    const float* imgs      = (const float*)d_in[0];
    const float* patch_w   = (const float*)d_in[1];
    const float* patch_b   = (const float*)d_in[2];
    const float* cls_token = (const float*)d_in[3];
    const float* pos_embed = (const float*)d_in[4];
    const float* cnn_w     = (const float*)d_in[5];
    const float* cnn_b     = (const float*)d_in[6];
    const float* norm_w    = (const float*)d_in[7];
    const float* in_proj_w = (const float*)d_in[8];
    const float* conv_w    = (const float*)d_in[9];
    const float* conv_b    = (const float*)d_in[10];
    const float* x_proj_w  = (const float*)d_in[11];
    const float* dt_proj_w = (const float*)d_in[12];
    const float* dt_proj_b = (const float*)d_in[13];
    const float* A_log     = (const float*)d_in[14];
    const float* Dskip     = (const float*)d_in[15];
    const float* out_proj_w= (const float*)d_in[16];
    const float* norm_f_w  = (const float*)d_in[17];
    const float* head_w    = (const float*)d_in[18];
    const float* head_b    = (const float*)d_in[19];

    float* ws = (float*)d_ws;
    size_t off = 0;
    float* resid  = ws + off; off += (size_t)NTOK * E;
    float* xdb    = ws + off; off += (size_t)NTOK * 44;
    float* dtbuf  = ws + off; off += (size_t)NTOK * DI;             // f32 dt only
    float* ydt    = ws + off; off += (size_t)NTOK * DI * 2;  // packed {y_local,dtcum}
    float* hend   = ws + off; off += (size_t)BATCH * NCH * DI * S;  // [b][ch][n][d]
    float* hinit  = ws + off; off += (size_t)BATCH * NCH * DI * S;  // [b][ch][n][d]
    float* negA   = ws + off; off += (size_t)DEPTH * DI * S;        // [layer][n][d]
    float* dtw_t  = ws + off; off += (size_t)DEPTH * DI * R;        // [layer][r][d]
    float* hid32  = ws + off; off += (size_t)BATCH * E;             // compact last hidden
    int*   gflag  = (int*)(ws + off); off += (size_t)DEPTH * DI;    // [layer][d]
    unsigned short* xm_bf  = (unsigned short*)(ws + off); off += (size_t)NTOK * DI / 2;
    unsigned short* z_bf   = (unsigned short*)(ws + off); off += (size_t)NTOK * DI / 2;
    unsigned short* bf_buf = (unsigned short*)(ws + off); off += (size_t)NTOK * DI / 2;
    unsigned short* y32_bf = (unsigned short*)(ws + off); off += (size_t)BATCH * DI / 2 + 16;
    unsigned short* w_in  = (unsigned short*)(ws + off); off += (size_t)DEPTH * 2 * DI * E / 2;
    unsigned short* w_x   = (unsigned short*)(ws + off); off += (size_t)DEPTH * 44 * DI / 2 + 16;
    unsigned short* w_out = (unsigned short*)(ws + off); off += (size_t)DEPTH * E * DI / 2;

    // shared bf16 buffer, disjoint live ranges:
    // hn_bf: rmsnorm -> in_proj; xc_bf: conv -> scanA; y_bf: fixup -> out_proj
    unsigned short* hn_bf = bf_buf;   // [NTOK, E]
    unsigned short* xc_bf = bf_buf;   // [NTOK, DI]
    unsigned short* y_bf  = bf_buf;   // [NTOK, DI]

    {
        int ntot = DEPTH * (2 * DI * E + 44 * DI + E * DI + DI * S + DI * R);
        k_prep<<<(ntot + 255) / 256, 256, 0, stream>>>(in_proj_w, x_proj_w, out_proj_w, A_log,
                                                       dt_proj_w, w_in, w_x, w_out, negA,
                                                       dtw_t);
        k_flag<<<(DEPTH * DI + 255) / 256, 256, 0, stream>>>(negA, gflag);
    }

    k_embed<<<(NTOK * E) / 256, 256, 0, stream>>>(imgs, patch_w, patch_b, cls_token,
                                                  pos_embed, cnn_w, cnn_b, resid);

    for (int i = 0; i < DEPTH; i++) {
        // hn = rmsnorm(resid)*w  (resid already includes all prior hiddens)
        k_rmsnorm<<<NTOK / 4, 256, 0, stream>>>(resid, hn_bf, norm_w + i * E);

        // in_proj: [NTOK,192]bf16 x [768,192]bf16^T -> split: xm bf16 + z bf16
        {
            dim3 g((2 * DI) / 64, (NTOK + 127) / 128);
            k_gemm_bf16<128, 64, 1><<<g, 256, 0, stream>>>(
                hn_bf, w_in + (size_t)i * 2 * DI * E, nullptr, xm_bf, z_bf, NTOK, 2 * DI, E);
        }
        // causal conv4 + silu -> xc_bf
        k_conv<<<(NTOK * DI) / 256, 256, 0, stream>>>(xm_bf, conv_w + (size_t)i * DI * 4,
                                                      conv_b + (size_t)i * DI, xc_bf);
        // x_proj: [NTOK,384]bf16 x [44,384]bf16^T -> xdb f32 [NTOK,44]
        {
            dim3 g(1, NTOK / 32);
            k_gemm_bf16<32, 64, 0><<<g, 256, 0, stream>>>(
                xc_bf, w_x + (size_t)i * 44 * DI, xdb, nullptr, nullptr, NTOK, 44, DI);
        }
        const float* nA = negA + (size_t)i * DI * S;
        const int* fl = gflag + (size_t)i * DI;
        // dt_proj + softplus -> f32 dt (block per token, throughput-parallel)
        k_dtpre<<<NTOK, 384, 0, stream>>>(xdb, dtw_t + (size_t)i * DI * R,
                                          dt_proj_b + (size_t)i * DI, dtbuf);
        // chunked scan: local scan -> chunk combine -> parallel fixup
        dim3 g(NCH, BATCH);
        if (i < DEPTH - 1) {
            k_scanA<false><<<g, DI, 0, stream>>>(xc_bf, xdb, dtbuf, nA, fl,
                                                 Dskip + (size_t)i * DI, (float2*)ydt, hend);
            k_scanB<<<(BATCH * DI + 255) / 256, 256, 0, stream>>>(hend, (const float2*)ydt,
                                                                  nA, fl, hinit);
            k_fixup<<<NTOK, 384, 0, stream>>>(z_bf, xdb, nA, fl, hinit,
                                              (const float2*)ydt, y_bf);
            // out_proj + residual accumulate: resid += y_bf @ w_out^T
            dim3 go(E / 64, (NTOK + 63) / 64);
            k_gemm_bf16<64, 64, 2><<<go, 256, 0, stream>>>(
                y_bf, w_out + (size_t)i * E * DI, resid, nullptr, nullptr, NTOK, E, DI);
        } else {
            // last layer: only the cls token (P) of each batch feeds the head
            k_scanA<true><<<g, DI, 0, stream>>>(xc_bf, xdb, dtbuf, nA, fl,
                                                Dskip + (size_t)i * DI, (float2*)ydt, hend);
            k_scanB<<<(BATCH * DI + 255) / 256, 256, 0, stream>>>(hend, (const float2*)ydt,
                                                                  nA, fl, hinit);
            k_fixup_last<<<BATCH, 384, 0, stream>>>(z_bf, xdb, nA, fl, hinit,
                                                    (const float2*)ydt, y32_bf);
            // out_proj on 32 rows only: [32,384] x [192,384]^T -> hid32 [32,192]
            dim3 go(E / 64, 1);
            k_gemm_bf16<32, 64, 0><<<go, 256, 0, stream>>>(
                y32_bf, w_out + (size_t)i * E * DI, hid32, nullptr, nullptr, BATCH, E, DI);
        }
    }

    k_head<<<BATCH, 64, 0, stream>>>(resid, hid32, norm_f_w, head_w, head_b, (float*)d_out);
}